// Round 6
// baseline (283.270 us; speedup 1.0000x reference)
//
#include <hip/hip_runtime.h>
#include <math.h>

#define H 128

typedef _Float16 half8 __attribute__((ext_vector_type(8)));
typedef float f32x16 __attribute__((ext_vector_type(16)));
typedef int int4v __attribute__((ext_vector_type(4)));

__device__ __forceinline__ half8 h8max(half8 a, half8 b) {
#if defined(__has_builtin) && __has_builtin(__builtin_elementwise_max)
    return __builtin_elementwise_max(a, b);
#else
    half8 r;
#pragma unroll
    for (int j = 0; j < 8; ++j) r[j] = a[j] > b[j] ? a[j] : b[j];
    return r;
#endif
}

__device__ __forceinline__ half8 h8shfl_xor(half8 v, int mask) {
    int4v iv;
    __builtin_memcpy(&iv, &v, 16);
#pragma unroll
    for (int j = 0; j < 4; ++j) iv[j] = __shfl_xor(iv[j], mask, 64);
    half8 r;
    __builtin_memcpy(&r, &iv, 16);
    return r;
}

// ---------------- CSR build ----------------

__global__ __launch_bounds__(256) void scan_atomic(const int* __restrict__ deg,
                                                   int* __restrict__ offsets,
                                                   int* __restrict__ gcur, int N) {
    __shared__ int buf[256];
    __shared__ int sbase;
    int tid = threadIdx.x;
    int i = blockIdx.x * 256 + tid;
    int v = (i < N) ? deg[i] : 0;
    int incl = v;
    buf[tid] = v;
    __syncthreads();
#pragma unroll
    for (int off = 1; off < 256; off <<= 1) {
        int t = (tid >= off) ? buf[tid - off] : 0;
        __syncthreads();
        incl += t;
        buf[tid] = incl;
        __syncthreads();
    }
    if (tid == 255) sbase = atomicAdd(gcur, incl);
    __syncthreads();
    if (i < N) offsets[i] = sbase + incl - v;
}

// fill CSR adj AND the padded 32-slot table directly (unsorted slots;
// segment-max is order/duplicate-insensitive). adjp32 rows pre-zeroed so
// unwritten slots point at node 0 (valid memory; clamped/overridden at read).
__global__ __launch_bounds__(256) void fill_adj(const int* __restrict__ ei, int E,
                                                const int* __restrict__ offsets,
                                                int* __restrict__ cursor,
                                                int* __restrict__ adj,
                                                int* __restrict__ adjp32) {
    int e = blockIdx.x * 256 + threadIdx.x;
    if (e < E) {
        int s = ei[e];
        int d = ei[E + e];
        int pos = atomicAdd(&cursor[d], 1);
        adj[offsets[d] + pos] = s;
        if (pos < 32) adjp32[(size_t)d * 32 + pos] = s;
    }
}

// ---------------- merged prep ----------------
// Weight image (all 7 mats, incl. Wlin): WAVE-LINEAR layout. Per mat 32768
// halves: [kc4:4][s = ks*4+colgrp :8][lane:64][hi8|lo8]. A wave-iteration
// (kc4,ks,colgrp=w) reads a dense 2 KB: Bimg[kc4*8192 + s*1024 + lane*16].
// Fragment (lhi=lane>>5,l31=lane&31): n=colgrp*32+l31, g16=kc4*4+ks*2+lhi,
// hi/lo halves of W[n][g16*8..+7].

__global__ __launch_bounds__(256) void prep_all(
    const int* __restrict__ ei, int E, int* __restrict__ deg,
    const float* __restrict__ x, const float* __restrict__ query,
    const float* __restrict__ Wl, const float* __restrict__ Wr,
    const float* __restrict__ Wlin, _Float16* __restrict__ xh,
    _Float16* __restrict__ wimg, float* __restrict__ qn, int n8, int HB, int SB,
    int WB) {
    int b = blockIdx.x;
    int tid = threadIdx.x;
    if (b < HB) {
        int e = b * 256 + tid;
        if (e < E) atomicAdd(&deg[ei[E + e]], 1);
    } else if (b < HB + SB) {
        int i = (b - HB) * 256 + tid;
        if (i < n8) {
            const float4* x4 = (const float4*)x;
            float4 u = x4[(size_t)i * 2], v = x4[(size_t)i * 2 + 1];
            float f[8] = {u.x, u.y, u.z, u.w, v.x, v.y, v.z, v.w};
            half8 h;
#pragma unroll
            for (int j = 0; j < 8; ++j) h[j] = (_Float16)f[j];
            *(half8*)(xh + (size_t)i * 8) = h;
        }
    } else if (b < HB + SB + WB) {
        int gidx = (b - HB - SB) * 256 + tid;
        if (gidx < 7 * 2048) {
            int mat = gidx / 2048;
            int rem = gidx - mat * 2048;
            int kc4 = rem >> 9;   // [0,4)
            int r2 = rem & 511;
            int s = r2 >> 6;      // [0,8) = ks*4 + colgrp
            int lane = r2 & 63;
            int ks = s >> 2;
            int colgrp = s & 3;
            int lhi = lane >> 5, l31 = lane & 31;
            int n = colgrp * 32 + l31;
            int g16 = kc4 * 4 + ks * 2 + lhi;
            const float* src = (mat == 6) ? Wlin
                             : ((mat & 1) ? Wr + (mat >> 1) * H * H
                                          : Wl + (mat >> 1) * H * H);
            const float* p = src + n * H + g16 * 8;
            half8 h, l;
#pragma unroll
            for (int j = 0; j < 8; ++j) {
                float v = p[j];
                _Float16 hh = (_Float16)v;
                h[j] = hh;
                l[j] = (_Float16)(v - (float)hh);
            }
            size_t base = (size_t)mat * 32768 + (size_t)kc4 * 8192 +
                          (size_t)s * 1024 + (size_t)lane * 16;
            *(half8*)(wimg + base) = h;
            *(half8*)(wimg + base + 8) = l;
        }
    } else {
        int g = b - HB - SB - WB;
        __shared__ float part[4];
        float v = (tid < 128) ? query[g * H + tid] : 0.f;
        float ss = v * v;
#pragma unroll
        for (int off = 32; off > 0; off >>= 1) ss += __shfl_xor(ss, off, 64);
        if ((tid & 63) == 0) part[tid >> 6] = ss;
        __syncthreads();
        float tot = part[0] + part[1];
        if (tid < 128) qn[g * H + tid] = v / fmaxf(sqrtf(tot), 1e-12f);
    }
}

// ---------------- fused layer v7 (+ optional final linear/cosine) ---------
// Y = relu(segmax(X) @ Wl^T + bias + X @ Wr^T).
// 32-row tile, 4 waves each owning a 32-col quarter; B dense from the
// wave-linear L2-resident image; sU/sX XOR-16 LDS images; unsorted padded
// adjp32 gather with read-time clamp (slot j<d ? j : 0).
// FINAL: layer-3 output stays in registers -> relu'd Y3 image into sU,
// 8 dense iterations vs Wlin image, cosine epilogue with 1 KB LDS combine.
// Deletes the standalone final kernel (391 blocks = 1.5/CU, latency-bound)
// and the 25.6 MB Y3 round-trip.

template <bool FINAL>
__global__ __launch_bounds__(256, 6) void layer_fused(
    const half8* __restrict__ Xh, const int* __restrict__ deg,
    const int* __restrict__ offsets, const int* __restrict__ adj,
    const int* __restrict__ adjp32, const _Float16* __restrict__ Bimg,
    const float* __restrict__ bias, _Float16* __restrict__ Yh,
    const _Float16* __restrict__ BimgF, const float* __restrict__ blin,
    const float* __restrict__ qn, const int* __restrict__ bv,
    float* __restrict__ out, int N) {
    __shared__ __align__(16) _Float16 sU[4096];  // m / Y3 image (32x128, XOR-16)
    __shared__ __align__(16) _Float16 sX[4096];  // x image (32x128, XOR-16)

    int tid = threadIdx.x;
    int w = tid >> 6;
    int lane = tid & 63;
    int l31 = lane & 31;
    int lhi = lane >> 5;
    int n0 = blockIdx.x * 32;

    const half8 hz = {(_Float16)0.f, (_Float16)0.f, (_Float16)0.f, (_Float16)0.f,
                      (_Float16)0.f, (_Float16)0.f, (_Float16)0.f, (_Float16)0.f};

    // ---- stage sX first: independent loads overlap gather metadata RT ----
    {
#pragma unroll
        for (int t = 0; t < 2; ++t) {
            int idx = tid + t * 256;  // [0,512)
            int row = idx >> 4;       // [0,32)
            int g = idx & 15;
            int nn = n0 + row;
            half8 h = hz;
            if (nn < N) h = Xh[(size_t)nn * 16 + g];
            *(half8*)&sX[row * 128 + ((g ^ (row & 15)) << 3)] = h;
        }
    }

    // ---- Phase G: gather segment-max (8 nodes per wave) ----
    {
        int sub = lane >> 4;
        int lf = lane & 15;
        const _Float16 ni = (_Float16)(-INFINITY);
        const half8 ninf = {ni, ni, ni, ni, ni, ni, ni, ni};
        int nd8 = n0 + w * 8;
        int nn = nd8 + (lane & 7);
        int degv = (nn < N) ? deg[nn] : 0;

        int dmx = degv;
#pragma unroll
        for (int off = 1; off <= 4; off <<= 1) {
            int t = __shfl_xor(dmx, off, 64);
            dmx = t > dmx ? t : dmx;
        }

        if (dmx <= 32) {
            // dense padded rows: r0/r1 = slots 0..15 of nodes 0..3 / 4..7
            // (lane L holds node (L>>4), slot (L&15)); r2/r3 = slots 16..31.
            int c0 = nd8 + (lane >> 4);
            c0 = c0 < N ? c0 : N - 1;
            int c1 = nd8 + 4 + (lane >> 4);
            c1 = c1 < N ? c1 : N - 1;
            int r0 = adjp32[(size_t)c0 * 32 + (lane & 15)];
            int r1 = adjp32[(size_t)c1 * 32 + (lane & 15)];
            int r2 = adjp32[(size_t)c0 * 32 + 16 + (lane & 15)];
            int r3 = adjp32[(size_t)c1 * 32 + 16 + (lane & 15)];
#pragma unroll
            for (int i = 0; i < 8; ++i) {
                int d = __shfl(degv, i, 64);
                int base = (i & 3) << 4;
                // slots (unsorted): clamp invalid slot j>=d to slot 0 (valid
                // for d>0; d==0 result overridden below)
                int j0 = sub, j1 = 4 + sub, j2 = 8 + sub, j3 = 12 + sub;
                int i0 = __shfl(i < 4 ? r0 : r1, base | (j0 < d ? j0 : 0), 64);
                int i1 = __shfl(i < 4 ? r0 : r1, base | (j1 < d ? j1 : 0), 64);
                int i2 = __shfl(i < 4 ? r0 : r1, base | (j2 < d ? j2 : 0), 64);
                int i3 = __shfl(i < 4 ? r0 : r1, base | (j3 < d ? j3 : 0), 64);
                half8 v0 = Xh[(size_t)i0 * 16 + lf];
                half8 v1 = Xh[(size_t)i1 * 16 + lf];
                half8 v2 = Xh[(size_t)i2 * 16 + lf];
                half8 v3 = Xh[(size_t)i3 * 16 + lf];
                half8 acc = h8max(h8max(v0, v1), h8max(v2, v3));
                if (d > 16) {  // wave-uniform per node; slot 16 valid here
                    int k4 = (16 + sub) < d ? sub : 0;
                    int k5 = (20 + sub) < d ? 4 + sub : 0;
                    int k6 = (24 + sub) < d ? 8 + sub : 0;
                    int k7 = (28 + sub) < d ? 12 + sub : 0;
                    int i4 = __shfl(i < 4 ? r2 : r3, base | k4, 64);
                    int i5 = __shfl(i < 4 ? r2 : r3, base | k5, 64);
                    int i6 = __shfl(i < 4 ? r2 : r3, base | k6, 64);
                    int i7 = __shfl(i < 4 ? r2 : r3, base | k7, 64);
                    half8 u0 = Xh[(size_t)i4 * 16 + lf];
                    half8 u1 = Xh[(size_t)i5 * 16 + lf];
                    half8 u2 = Xh[(size_t)i6 * 16 + lf];
                    half8 u3 = Xh[(size_t)i7 * 16 + lf];
                    acc = h8max(acc, h8max(h8max(u0, u1), h8max(u2, u3)));
                }
                acc = h8max(acc, h8shfl_xor(acc, 16));
                acc = h8max(acc, h8shfl_xor(acc, 32));
                if (d == 0) acc = hz;
                int row = w * 8 + i;
                if (sub == 0) *(half8*)&sU[row * 128 + ((lf ^ (row & 15)) << 3)] = acc;
            }
        } else {
            // general path (rare): wave-per-node CSR loop
            int ndc = nn < N ? nn : N - 1;
            int e0v = offsets[ndc];
            for (int i = 0; i < 8; ++i) {
                int e0 = __shfl(e0v, i, 64);
                int d = __shfl(degv, i, 64);
                int row = w * 8 + i;
                half8 acc = ninf;
                for (int base = 0; base < d; base += 16) {
                    half8 v[4];
#pragma unroll
                    for (int q = 0; q < 4; ++q) {
                        int j = base + q * 4 + sub;
                        int idx = adj[e0 + (j < d ? j : d - 1)];
                        v[q] = Xh[(size_t)idx * 16 + lf];
                    }
                    acc = h8max(acc, h8max(h8max(v[0], v[1]), h8max(v[2], v[3])));
                }
                acc = h8max(acc, h8shfl_xor(acc, 16));
                acc = h8max(acc, h8shfl_xor(acc, 32));
                if (d == 0) acc = hz;
                if (sub == 0) *(half8*)&sU[row * 128 + ((lf ^ (row & 15)) << 3)] = acc;
            }
        }
    }
    __syncthreads();  // sU + sX both visible

    f32x16 acc;
    {
        float bvv = bias[w * 32 + l31];
#pragma unroll
        for (int r = 0; r < 16; ++r) acc[r] = bvv;
    }

    int rl = l31;            // this lane's A row within the tile
    int col = w * 32 + l31;  // this lane's output column

    // ---- Pass 0: m @ Wl^T (A from sU, B dense-global) ----
#pragma unroll
    for (int kc4 = 0; kc4 < 4; ++kc4) {
#pragma unroll
        for (int ks = 0; ks < 2; ++ks) {
            int g16 = kc4 * 4 + ks * 2 + lhi;
            int posA = g16 ^ (rl & 15);
            half8 ah = *(const half8*)&sU[rl * 128 + posA * 8];
            size_t boff =
                (size_t)kc4 * 8192 + (size_t)(ks * 4 + w) * 1024 + (size_t)lane * 16;
            half8 bh = *(const half8*)&Bimg[boff];
            half8 bl2 = *(const half8*)&Bimg[boff + 8];
            acc = __builtin_amdgcn_mfma_f32_32x32x16_f16(ah, bh, acc, 0, 0, 0);
            acc = __builtin_amdgcn_mfma_f32_32x32x16_f16(ah, bl2, acc, 0, 0, 0);
        }
    }

    // ---- Pass 1: x @ Wr^T (A from sX, B dense-global) ----
    const _Float16* Br = Bimg + 32768;
#pragma unroll
    for (int kc4 = 0; kc4 < 4; ++kc4) {
#pragma unroll
        for (int ks = 0; ks < 2; ++ks) {
            int g16 = kc4 * 4 + ks * 2 + lhi;
            int posA = g16 ^ (rl & 15);
            half8 ah = *(const half8*)&sX[rl * 128 + posA * 8];
            size_t boff =
                (size_t)kc4 * 8192 + (size_t)(ks * 4 + w) * 1024 + (size_t)lane * 16;
            half8 bh = *(const half8*)&Br[boff];
            half8 bl2 = *(const half8*)&Br[boff + 8];
            acc = __builtin_amdgcn_mfma_f32_32x32x16_f16(ah, bh, acc, 0, 0, 0);
            acc = __builtin_amdgcn_mfma_f32_32x32x16_f16(ah, bl2, acc, 0, 0, 0);
        }
    }

    if constexpr (!FINAL) {
        // epilogue: relu + fp16 store. C/D 32x32: row=(r&3)+8*(r>>2)+4*lhi
#pragma unroll
        for (int r = 0; r < 16; ++r) {
            int row = n0 + (r & 3) + 8 * (r >> 2) + 4 * lhi;
            if (row < N) Yh[(size_t)row * H + col] = (_Float16)fmaxf(acc[r], 0.f);
        }
    } else {
        // ---- FINAL phase: Y3 stays on-chip ----
        __syncthreads();  // all pass-0/1 sU/sX reads complete
        // relu'd Y3 -> sU as XOR-16 image (same convention as staging)
#pragma unroll
        for (int r = 0; r < 16; ++r) {
            int rloc = (r & 3) + 8 * (r >> 2) + 4 * lhi;
            sU[rloc * 128 + (((col >> 3) ^ (rloc & 15)) << 3) + (col & 7)] =
                (_Float16)fmaxf(acc[r], 0.f);
        }
        f32x16 acc2;
        {
            float b = blin[col];
#pragma unroll
            for (int r = 0; r < 16; ++r) acc2[r] = b;
        }
        int arow = n0 + l31;
        arow = arow < N ? arow : N - 1;
        int gl = bv[arow];  // block-row l31's graph id
        __syncthreads();    // Y3 image visible; sX free for reuse

        // ---- Pass F: Y3 @ Wlin^T (A from sU, B dense-global) ----
#pragma unroll
        for (int kc4 = 0; kc4 < 4; ++kc4) {
#pragma unroll
            for (int ks = 0; ks < 2; ++ks) {
                int g16 = kc4 * 4 + ks * 2 + lhi;
                int posA = g16 ^ (rl & 15);
                half8 ah = *(const half8*)&sU[rl * 128 + posA * 8];
                size_t boff = (size_t)kc4 * 8192 + (size_t)(ks * 4 + w) * 1024 +
                              (size_t)lane * 16;
                half8 bh = *(const half8*)&BimgF[boff];
                half8 bl2 = *(const half8*)&BimgF[boff + 8];
                acc2 = __builtin_amdgcn_mfma_f32_32x32x16_f16(ah, bh, acc2, 0, 0, 0);
                acc2 = __builtin_amdgcn_mfma_f32_32x32x16_f16(ah, bl2, acc2, 0, 0, 0);
            }
        }

        // ---- cosine epilogue: per-quarter partials, combine via LDS ----
        float* sP = (float*)sX;  // [32 rows][4 quarters][ss,sd] = 1 KB
#pragma unroll
        for (int r = 0; r < 16; ++r) {
            int rloc = (r & 3) + 8 * (r >> 2) + 4 * lhi;
            int g = __shfl(gl, rloc, 32);
            float y = acc2[r];
            float q = qn[(size_t)g * H + col];
            float ss = y * y;
            float sd = y * q;
#pragma unroll
            for (int off = 1; off <= 16; off <<= 1) {
                ss += __shfl_xor(ss, off, 64);
                sd += __shfl_xor(sd, off, 64);
            }
            if (l31 == 0) {
                sP[(rloc * 4 + w) * 2] = ss;
                sP[(rloc * 4 + w) * 2 + 1] = sd;
            }
        }
        __syncthreads();
        if (tid < 32) {
            int row = n0 + tid;
            if (row < N) {
                float ss = 0.f, sd = 0.f;
#pragma unroll
                for (int q = 0; q < 4; ++q) {
                    ss += sP[(tid * 4 + q) * 2];
                    sd += sP[(tid * 4 + q) * 2 + 1];
                }
                out[row] = sd / fmaxf(sqrtf(ss), 1e-12f);
            }
        }
    }
}

// ---------------- launch ----------------

extern "C" void kernel_launch(void* const* d_in, const int* in_sizes, int n_in,
                              void* d_out, int out_size, void* d_ws, size_t ws_size,
                              hipStream_t stream) {
    const float* x = (const float*)d_in[0];
    const float* query = (const float*)d_in[1];
    const float* Wl = (const float*)d_in[2];
    const float* bl = (const float*)d_in[3];
    const float* Wr = (const float*)d_in[4];
    const float* Wlin = (const float*)d_in[5];
    const float* blin = (const float*)d_in[6];
    const int* ei = (const int*)d_in[7];
    const int* bv = (const int*)d_in[8];
    float* out = (float*)d_out;

    const int N = in_sizes[0] / H;
    const int E = in_sizes[7] / 2;
    const int G = in_sizes[1] / H;

    char* p = (char*)d_ws;
    auto alloc = [&](size_t bytes) {
        char* r = p;
        p += (bytes + 255) & ~(size_t)255;
        return r;
    };
    int* deg = (int*)alloc((size_t)(2 * N + 1) * sizeof(int));  // deg|cursor|gcur
    int* cursor = deg + N;
    int* gcur = deg + 2 * N;
    int* offsets = (int*)alloc((size_t)N * sizeof(int));
    int* adj = (int*)alloc((size_t)E * sizeof(int));
    int* adjp32 = (int*)alloc((size_t)N * 32 * sizeof(int));
    float* qn = (float*)alloc((size_t)G * H * sizeof(float));
    _Float16* wimg = (_Float16*)alloc((size_t)7 * 32768 * sizeof(_Float16));
    size_t actH = (size_t)N * H * sizeof(_Float16);
    _Float16* xah = (_Float16*)alloc(actH);
    _Float16* xbh = (_Float16*)alloc(actH);

    hipMemsetAsync(deg, 0, (size_t)(2 * N + 1) * sizeof(int), stream);
    hipMemsetAsync(adjp32, 0, (size_t)N * 32 * sizeof(int), stream);

    const int n8 = N * H / 8;
    const int HB = (E + 255) / 256;
    const int SB = (n8 + 255) / 256;
    const int WB = (7 * 2048 + 255) / 256;
    prep_all<<<HB + SB + WB + G, 256, 0, stream>>>(ei, E, deg, x, query, Wl, Wr,
                                                   Wlin, xah, wimg, qn, n8, HB,
                                                   SB, WB);
    scan_atomic<<<(N + 255) / 256, 256, 0, stream>>>(deg, offsets, gcur, N);
    fill_adj<<<(E + 255) / 256, 256, 0, stream>>>(ei, E, offsets, cursor, adj,
                                                  adjp32);

    const int NGm = (N + 31) / 32;  // 32-row tiles

    layer_fused<false><<<NGm, 256, 0, stream>>>(
        (const half8*)xah, deg, offsets, adj, adjp32, wimg + (size_t)0 * 65536,
        bl + 0 * H, xbh, nullptr, nullptr, nullptr, nullptr, nullptr, N);
    layer_fused<false><<<NGm, 256, 0, stream>>>(
        (const half8*)xbh, deg, offsets, adj, adjp32, wimg + (size_t)1 * 65536,
        bl + 1 * H, xah, nullptr, nullptr, nullptr, nullptr, nullptr, N);
    layer_fused<true><<<NGm, 256, 0, stream>>>(
        (const half8*)xah, deg, offsets, adj, adjp32, wimg + (size_t)2 * 65536,
        bl + 2 * H, nullptr, wimg + (size_t)6 * 32768, blin, qn, bv, out, N);
}